// Round 1
// baseline (9114.124 us; speedup 1.0000x reference)
//
#include <hip/hip_runtime.h>
#include <math.h>

#define N_NODES 50000
#define N_EDGES 1600000
#define IN_C    1433
#define HID_C   128
#define OUT_C   47

// ---------------- degree / norm ----------------
__global__ __launch_bounds__(256) void k_init_deg(float* deg) {
    int i = blockIdx.x * 256 + threadIdx.x;
    if (i < N_NODES) deg[i] = 1.0f;   // self-loop contributes 1
}

__global__ __launch_bounds__(256) void k_count(const int* __restrict__ dst, float* deg) {
    int e = blockIdx.x * 256 + threadIdx.x;
    if (e < N_EDGES) atomicAdd(&deg[dst[e]], 1.0f);
}

__global__ __launch_bounds__(256) void k_dinv(float* deg) {
    int i = blockIdx.x * 256 + threadIdx.x;
    if (i < N_NODES) deg[i] = 1.0f / sqrtf(deg[i]);   // deg >= 1 always
}

// ---------------- tiled fp32 GEMM ----------------
// C[M,N] = (RELU_A ? relu(A) : A)[M,K] @ B[K,N]  (+ bias[n] if BIAS)
// BM=64, BK=16, block=256 (16x16 threads), per-thread 4 rows x (BN/16) cols.
template<int BN, bool RELU_A, bool BIAS>
__global__ __launch_bounds__(256) void k_gemm(
    const float* __restrict__ A, const float* __restrict__ B,
    const float* __restrict__ bias, float* __restrict__ C,
    int M, int N, int K, int lda, int ldb, int ldc)
{
    constexpr int BM = 64, BK = 16;
    constexpr int TNV = BN / 64;              // float4 col groups per thread
    __shared__ float As[BK][BM + 4];          // stride 68 floats (272B, 16B-aligned)
    __shared__ float Bs[BK][BN];

    const int tid = threadIdx.x;
    const int tm = tid >> 4;                  // 0..15
    const int tn = tid & 15;                  // 0..15
    const int m0 = blockIdx.x * BM;
    const int n0 = blockIdx.y * BN;

    float acc[4][TNV * 4];
#pragma unroll
    for (int r = 0; r < 4; ++r)
#pragma unroll
        for (int c = 0; c < TNV * 4; ++c) acc[r][c] = 0.f;

    for (int k0 = 0; k0 < K; k0 += BK) {
        // stage A tile (transposed into LDS)
        {
            int kk = tid & 15;
            int r0 = tid >> 4;
#pragma unroll
            for (int it = 0; it < 4; ++it) {
                int r = r0 + 16 * it;
                int gm = m0 + r, gk = k0 + kk;
                float v = 0.f;
                if (gm < M && gk < K) v = A[(long)gm * lda + gk];
                if (RELU_A) v = fmaxf(v, 0.f);
                As[kk][r] = v;
            }
        }
        // stage B tile
        {
            constexpr int KPP = 256 / BN;     // k-rows per pass
            int n  = tid % BN;
            int kb = tid / BN;
#pragma unroll
            for (int it = 0; it < BK / KPP; ++it) {
                int kk = kb + KPP * it;
                int gk = k0 + kk, gn = n0 + n;
                float v = 0.f;
                if (gk < K && gn < N) v = B[(long)gk * ldb + gn];
                Bs[kk][n] = v;
            }
        }
        __syncthreads();
#pragma unroll
        for (int kk = 0; kk < BK; ++kk) {
            float4 a = *(const float4*)&As[kk][tm * 4];
            float av[4] = {a.x, a.y, a.z, a.w};
#pragma unroll
            for (int j = 0; j < TNV; ++j) {
                float4 b = *(const float4*)&Bs[kk][tn * 4 + 64 * j];
                float bv[4] = {b.x, b.y, b.z, b.w};
#pragma unroll
                for (int r = 0; r < 4; ++r)
#pragma unroll
                    for (int c = 0; c < 4; ++c)
                        acc[r][c + j * 4] += av[r] * bv[c];
            }
        }
        __syncthreads();
    }
    // store
#pragma unroll
    for (int r = 0; r < 4; ++r) {
        int gm = m0 + tm * 4 + r;
        if (gm >= M) continue;
#pragma unroll
        for (int j = 0; j < TNV; ++j)
#pragma unroll
            for (int c = 0; c < 4; ++c) {
                int gn = n0 + tn * 4 + 64 * j + c;
                if (gn < N) {
                    float v = acc[r][c + j * 4];
                    if (BIAS) v += bias[gn];
                    C[(long)gm * ldc + gn] = v;
                }
            }
    }
}

// ---------------- self-loop init: out[i][:] = (bias) + f(in[i][:]) * dinv[i]^2 ----------------
template<bool RELU_IN, bool BIAS>
__global__ __launch_bounds__(256) void k_selfloop(
    const float4* __restrict__ in, const float* __restrict__ dinv,
    const float* __restrict__ bias, float4* __restrict__ out)
{
    int idx = blockIdx.x * 256 + threadIdx.x;       // N_NODES * 32 float4s
    if (idx >= N_NODES * (HID_C / 4)) return;
    int i = idx >> 5, q = idx & 31;
    float d = dinv[i];
    float w = d * d;
    float4 v = in[idx];
    if (RELU_IN) {
        v.x = fmaxf(v.x, 0.f); v.y = fmaxf(v.y, 0.f);
        v.z = fmaxf(v.z, 0.f); v.w = fmaxf(v.w, 0.f);
    }
    float4 b = {0.f, 0.f, 0.f, 0.f};
    if (BIAS) b = *(const float4*)&bias[q * 4];
    out[idx] = float4{b.x + v.x * w, b.y + v.y * w, b.z + v.z * w, b.w + v.w * w};
}

// ---------------- edge scatter: h[dst] += f(hw[src]) * dinv[src]*dinv[dst] ----------------
template<bool RELU_IN>
__global__ __launch_bounds__(256) void k_scatter(
    const int* __restrict__ src, const int* __restrict__ dst,
    const float* __restrict__ dinv, const float4* __restrict__ hw,
    float* __restrict__ h)
{
    int tid = threadIdx.x;
    int e = blockIdx.x * 8 + (tid >> 5);
    if (e >= N_EDGES) return;
    int lane = tid & 31;
    int s = src[e], t = dst[e];
    float w = dinv[s] * dinv[t];
    float4 v = hw[s * 32 + lane];
    if (RELU_IN) {
        v.x = fmaxf(v.x, 0.f); v.y = fmaxf(v.y, 0.f);
        v.z = fmaxf(v.z, 0.f); v.w = fmaxf(v.w, 0.f);
    }
    float* p = h + (long)t * HID_C + lane * 4;
    atomicAdd(p + 0, v.x * w);
    atomicAdd(p + 1, v.y * w);
    atomicAdd(p + 2, v.z * w);
    atomicAdd(p + 3, v.w * w);
}

extern "C" void kernel_launch(void* const* d_in, const int* in_sizes, int n_in,
                              void* d_out, int out_size, void* d_ws, size_t ws_size,
                              hipStream_t stream) {
    const float* x  = (const float*)d_in[0];
    const int*   ei = (const int*)  d_in[1];
    const float* W1 = (const float*)d_in[2];
    const float* b1 = (const float*)d_in[3];
    const float* W2 = (const float*)d_in[4];
    const float* b2 = (const float*)d_in[5];
    const float* W3 = (const float*)d_in[6];
    const float* b3 = (const float*)d_in[7];
    float* out = (float*)d_out;
    const int* src = ei;
    const int* dst = ei + N_EDGES;

    char* ws = (char*)d_ws;
    float* dinv = (float*)ws;                              // 200 KB
    float* bufA = (float*)(ws + (1u << 20));               // 25.6 MB
    float* bufB = (float*)(ws + (1u << 20) + (32u << 20)); // 25.6 MB

    dim3 blk(256);
    const int gN  = (N_NODES + 255) / 256;                 // 196
    const int gE  = (N_EDGES + 255) / 256;                 // 6250
    const int gNC = (N_NODES * (HID_C / 4) + 255) / 256;   // 6250
    const int gSc = N_EDGES / 8;                           // 200000
    dim3 gGemm((N_NODES + 63) / 64, 1);                    // 782

    // norm
    k_init_deg<<<gN, blk, 0, stream>>>(dinv);
    k_count<<<gE, blk, 0, stream>>>(dst, dinv);
    k_dinv<<<gN, blk, 0, stream>>>(dinv);

    // layer 1: hw1 = x @ W1 ; h1 = b1 + selfloop + scatter  (relu deferred to GEMM2 load)
    k_gemm<128, false, false><<<gGemm, blk, 0, stream>>>(
        x, W1, nullptr, bufA, N_NODES, HID_C, IN_C, IN_C, HID_C, HID_C);
    k_selfloop<false, true><<<gNC, blk, 0, stream>>>((const float4*)bufA, dinv, b1, (float4*)bufB);
    k_scatter<false><<<gSc, blk, 0, stream>>>(src, dst, dinv, (const float4*)bufA, bufB);

    // layer 2: hw2 = relu(h1) @ W2 ; h2 = b2 + selfloop + scatter
    k_gemm<128, true, false><<<gGemm, blk, 0, stream>>>(
        bufB, W2, nullptr, bufA, N_NODES, HID_C, HID_C, HID_C, HID_C, HID_C);
    k_selfloop<false, true><<<gNC, blk, 0, stream>>>((const float4*)bufA, dinv, b2, (float4*)bufB);
    k_scatter<false><<<gSc, blk, 0, stream>>>(src, dst, dinv, (const float4*)bufA, bufB);

    // layer 3: associativity: out = (agg(relu(h2))) @ W3 + b3
    k_selfloop<true, false><<<gNC, blk, 0, stream>>>((const float4*)bufB, dinv, nullptr, (float4*)bufA);
    k_scatter<true><<<gSc, blk, 0, stream>>>(src, dst, dinv, (const float4*)bufB, bufA);
    k_gemm<64, false, true><<<gGemm, blk, 0, stream>>>(
        bufA, W3, b3, out, N_NODES, OUT_C, HID_C, HID_C, OUT_C, OUT_C);
}

// Round 2
// 1570.656 us; speedup vs baseline: 5.8027x; 5.8027x over previous
//
#include <hip/hip_runtime.h>
#include <math.h>

#define N_NODES 50000
#define N_EDGES 1600000
#define IN_C    1433
#define HID_C   128
#define OUT_C   47

// ---------------- utility ----------------
__global__ __launch_bounds__(256) void k_zero_i(int* p, int n) {
    int i = blockIdx.x * 256 + threadIdx.x;
    if (i < n) p[i] = 0;
}

__global__ __launch_bounds__(256) void k_count(const int* __restrict__ dst, int* __restrict__ cnt) {
    int e = blockIdx.x * 256 + threadIdx.x;
    if (e < N_EDGES) atomicAdd(&cnt[dst[e]], 1);
}

__global__ __launch_bounds__(256) void k_dinv(const int* __restrict__ cnt, float* __restrict__ dinv) {
    int i = blockIdx.x * 256 + threadIdx.x;
    if (i < N_NODES) dinv[i] = rsqrtf(1.0f + (float)cnt[i]);   // +1 self-loop
}

// single-block hierarchical exclusive scan of cnt[50000] -> row_start[50001]
__global__ __launch_bounds__(1024) void k_scan(const int* __restrict__ cnt, int* __restrict__ row_start) {
    __shared__ int sums[1024];
    const int t = threadIdx.x;
    const int CH = (N_NODES + 1023) / 1024;    // 49
    const int base = t * CH;
    int s = 0;
    for (int j = 0; j < CH; ++j) {
        int idx = base + j;
        if (idx < N_NODES) s += cnt[idx];
    }
    sums[t] = s;
    __syncthreads();
    for (int off = 1; off < 1024; off <<= 1) {
        int v = (t >= off) ? sums[t - off] : 0;
        __syncthreads();
        sums[t] += v;
        __syncthreads();
    }
    int run = (t == 0) ? 0 : sums[t - 1];
    for (int j = 0; j < CH; ++j) {
        int idx = base + j;
        if (idx < N_NODES) { row_start[idx] = run; run += cnt[idx]; }
    }
    if (t == 1023) row_start[N_NODES] = N_EDGES;
}

__global__ __launch_bounds__(256) void k_fill(
    const int* __restrict__ src, const int* __restrict__ dst,
    const int* __restrict__ row_start, int* __restrict__ cursor,
    int* __restrict__ csr_src)
{
    int e = blockIdx.x * 256 + threadIdx.x;
    if (e >= N_EDGES) return;
    int t = dst[e];
    int pos = row_start[t] + atomicAdd(&cursor[t], 1);
    csr_src[pos] = src[e];
}

// ---------------- tiled fp32 GEMM ----------------
// C[M,N] = (RELU_A ? relu(A) : A)[M,K] @ B[K,N]  (+ bias[n] if BIAS)
template<int BN, bool RELU_A, bool BIAS>
__global__ __launch_bounds__(256) void k_gemm(
    const float* __restrict__ A, const float* __restrict__ B,
    const float* __restrict__ bias, float* __restrict__ C,
    int M, int N, int K, int lda, int ldb, int ldc)
{
    constexpr int BM = 64, BK = 16;
    constexpr int TNV = BN / 64;
    __shared__ float As[BK][BM + 4];
    __shared__ float Bs[BK][BN];

    const int tid = threadIdx.x;
    const int tm = tid >> 4;
    const int tn = tid & 15;
    const int m0 = blockIdx.x * BM;
    const int n0 = blockIdx.y * BN;

    float acc[4][TNV * 4];
#pragma unroll
    for (int r = 0; r < 4; ++r)
#pragma unroll
        for (int c = 0; c < TNV * 4; ++c) acc[r][c] = 0.f;

    for (int k0 = 0; k0 < K; k0 += BK) {
        {
            int kk = tid & 15;
            int r0 = tid >> 4;
#pragma unroll
            for (int it = 0; it < 4; ++it) {
                int r = r0 + 16 * it;
                int gm = m0 + r, gk = k0 + kk;
                float v = 0.f;
                if (gm < M && gk < K) v = A[(long)gm * lda + gk];
                if (RELU_A) v = fmaxf(v, 0.f);
                As[kk][r] = v;
            }
        }
        {
            constexpr int KPP = 256 / BN;
            int n  = tid % BN;
            int kb = tid / BN;
#pragma unroll
            for (int it = 0; it < BK / KPP; ++it) {
                int kk = kb + KPP * it;
                int gk = k0 + kk, gn = n0 + n;
                float v = 0.f;
                if (gk < K && gn < N) v = B[(long)gk * ldb + gn];
                Bs[kk][n] = v;
            }
        }
        __syncthreads();
#pragma unroll
        for (int kk = 0; kk < BK; ++kk) {
            float4 a = *(const float4*)&As[kk][tm * 4];
            float av[4] = {a.x, a.y, a.z, a.w};
#pragma unroll
            for (int j = 0; j < TNV; ++j) {
                float4 b = *(const float4*)&Bs[kk][tn * 4 + 64 * j];
                float bv[4] = {b.x, b.y, b.z, b.w};
#pragma unroll
                for (int r = 0; r < 4; ++r)
#pragma unroll
                    for (int c = 0; c < 4; ++c)
                        acc[r][c + j * 4] += av[r] * bv[c];
            }
        }
        __syncthreads();
    }
#pragma unroll
    for (int r = 0; r < 4; ++r) {
        int gm = m0 + tm * 4 + r;
        if (gm >= M) continue;
#pragma unroll
        for (int j = 0; j < TNV; ++j)
#pragma unroll
            for (int c = 0; c < 4; ++c) {
                int gn = n0 + tn * 4 + 64 * j + c;
                if (gn < N) {
                    float v = acc[r][c + j * 4];
                    if (BIAS) v += bias[gn];
                    C[(long)gm * ldc + gn] = v;
                }
            }
    }
}

// ---------------- CSR gather-aggregate ----------------
// out[i] = bias + dinv[i] * ( sum_{e in in(i)} dinv[src_e]*f(hw[src_e])  +  dinv[i]*f(hw[i]) )
// one wave (64 lanes) per node; lane handles 2 channels (float2).
template<bool RELU_IN, bool BIAS>
__global__ __launch_bounds__(256) void k_aggregate(
    const float2* __restrict__ hw, const int* __restrict__ row_start,
    const int* __restrict__ csr_src, const float* __restrict__ dinv,
    const float* __restrict__ bias, float2* __restrict__ out)
{
    const int tid = threadIdx.x;
    const int node = blockIdx.x * 4 + (tid >> 6);
    if (node >= N_NODES) return;
    const int lane = tid & 63;

    float dt = dinv[node];
    float2 v = hw[(long)node * 64 + lane];
    if (RELU_IN) { v.x = fmaxf(v.x, 0.f); v.y = fmaxf(v.y, 0.f); }
    float2 acc = {0.f, 0.f};

    const int e1 = row_start[node + 1];
    int e = row_start[node];
    for (; e + 2 <= e1; e += 2) {
        int s0 = csr_src[e], s1 = csr_src[e + 1];
        float w0 = dinv[s0], w1 = dinv[s1];
        float2 u0 = hw[(long)s0 * 64 + lane];
        float2 u1 = hw[(long)s1 * 64 + lane];
        if (RELU_IN) {
            u0.x = fmaxf(u0.x, 0.f); u0.y = fmaxf(u0.y, 0.f);
            u1.x = fmaxf(u1.x, 0.f); u1.y = fmaxf(u1.y, 0.f);
        }
        acc.x += w0 * u0.x + w1 * u1.x;
        acc.y += w0 * u0.y + w1 * u1.y;
    }
    if (e < e1) {
        int s0 = csr_src[e];
        float w0 = dinv[s0];
        float2 u0 = hw[(long)s0 * 64 + lane];
        if (RELU_IN) { u0.x = fmaxf(u0.x, 0.f); u0.y = fmaxf(u0.y, 0.f); }
        acc.x += w0 * u0.x;
        acc.y += w0 * u0.y;
    }

    float2 r;
    r.x = dt * (acc.x + dt * v.x);
    r.y = dt * (acc.y + dt * v.y);
    if (BIAS) {
        float2 b = ((const float2*)bias)[lane];
        r.x += b.x; r.y += b.y;
    }
    out[(long)node * 64 + lane] = r;
}

extern "C" void kernel_launch(void* const* d_in, const int* in_sizes, int n_in,
                              void* d_out, int out_size, void* d_ws, size_t ws_size,
                              hipStream_t stream) {
    const float* x  = (const float*)d_in[0];
    const int*   ei = (const int*)  d_in[1];
    const float* W1 = (const float*)d_in[2];
    const float* b1 = (const float*)d_in[3];
    const float* W2 = (const float*)d_in[4];
    const float* b2 = (const float*)d_in[5];
    const float* W3 = (const float*)d_in[6];
    const float* b3 = (const float*)d_in[7];
    float* out = (float*)d_out;
    const int* src = ei;
    const int* dst = ei + N_EDGES;

    // workspace layout (bytes, 512-aligned chunks)
    char* ws = (char*)d_ws;
    float* dinv      = (float*)(ws + 0);              // 200,000 B
    int*   cnt       = (int*)  (ws + 200192);         // 200,000 B
    int*   cursor    = (int*)  (ws + 400384);         // 200,000 B
    int*   row_start = (int*)  (ws + 600576);         // 200,004 B
    int*   csr_src   = (int*)  (ws + 801280);         // 6,400,000 B
    float* bufA      = (float*)(ws + 7201280);        // 25,600,000 B
    float* bufB      = (float*)(ws + 32801280);       // 25,600,000 B  (ends ~58.4 MB)

    dim3 blk(256);
    const int gN  = (N_NODES + 255) / 256;            // 196
    const int gE  = (N_EDGES + 255) / 256;            // 6250
    const int gAg = (N_NODES + 3) / 4;                // 12500
    dim3 gGemm((N_NODES + 63) / 64, 1);               // 782

    // ---- CSR build (ws is re-poisoned each call: zero our counters) ----
    k_zero_i<<<(2 * N_NODES + 255) / 256, blk, 0, stream>>>(cnt, 2 * N_NODES); // wrong: cnt,cursor not adjacent-sized; zero separately below
    k_zero_i<<<gN, blk, 0, stream>>>(cursor, N_NODES);
    k_count<<<gE, blk, 0, stream>>>(dst, cnt);
    k_dinv<<<gN, blk, 0, stream>>>(cnt, dinv);
    k_scan<<<1, 1024, 0, stream>>>(cnt, row_start);
    k_fill<<<gE, blk, 0, stream>>>(src, dst, row_start, cursor, csr_src);

    // ---- layer 1: hw1 = x @ W1 ; h1 = Â·hw1 + b1 (relu deferred) ----
    k_gemm<128, false, false><<<gGemm, blk, 0, stream>>>(
        x, W1, nullptr, bufA, N_NODES, HID_C, IN_C, IN_C, HID_C, HID_C);
    k_aggregate<false, true><<<gAg, blk, 0, stream>>>(
        (const float2*)bufA, row_start, csr_src, dinv, b1, (float2*)bufB);

    // ---- layer 2: hw2 = relu(h1) @ W2 ; h2 = Â·hw2 + b2 ----
    k_gemm<128, true, false><<<gGemm, blk, 0, stream>>>(
        bufB, W2, nullptr, bufA, N_NODES, HID_C, HID_C, HID_C, HID_C, HID_C);
    k_aggregate<false, true><<<gAg, blk, 0, stream>>>(
        (const float2*)bufA, row_start, csr_src, dinv, b2, (float2*)bufB);

    // ---- layer 3: out = (Â·relu(h2)) @ W3 + b3 ----
    k_aggregate<true, false><<<gAg, blk, 0, stream>>>(
        (const float2*)bufB, row_start, csr_src, dinv, nullptr, (float2*)bufA);
    k_gemm<64, false, true><<<gGemm, blk, 0, stream>>>(
        bufA, W3, b3, out, N_NODES, OUT_C, HID_C, HID_C, OUT_C, OUT_C);
}

// Round 3
// 1242.231 us; speedup vs baseline: 7.3369x; 1.2644x over previous
//
#include <hip/hip_runtime.h>
#include <math.h>

#define N_NODES 50000
#define N_EDGES 1600000
#define IN_C    1433
#define HID_C   128
#define OUT_C   47
#define KPAD1   1440

typedef unsigned short u16;

// float -> bf16 (RNE), also returns the bf16 value re-expanded to float
__device__ inline u16 f2bf(float x, float& hf) {
    unsigned u = __float_as_uint(x);
    unsigned r = (u + 0x7FFFu + ((u >> 16) & 1u)) & 0xFFFF0000u;
    hf = __uint_as_float(r);
    return (u16)(r >> 16);
}

// ---------------- utility ----------------
__global__ __launch_bounds__(256) void k_zero_i(int* p, int n) {
    int i = blockIdx.x * 256 + threadIdx.x;
    if (i < n) p[i] = 0;
}

__global__ __launch_bounds__(256) void k_count(const int* __restrict__ dst, int* __restrict__ cnt) {
    int e = blockIdx.x * 256 + threadIdx.x;
    if (e < N_EDGES) atomicAdd(&cnt[dst[e]], 1);
}

__global__ __launch_bounds__(256) void k_dinv(const int* __restrict__ cnt, float* __restrict__ dinv) {
    int i = blockIdx.x * 256 + threadIdx.x;
    if (i < N_NODES) dinv[i] = rsqrtf(1.0f + (float)cnt[i]);
}

__global__ __launch_bounds__(1024) void k_scan(const int* __restrict__ cnt, int* __restrict__ row_start) {
    __shared__ int sums[1024];
    const int t = threadIdx.x;
    const int CH = (N_NODES + 1023) / 1024;
    const int base = t * CH;
    int s = 0;
    for (int j = 0; j < CH; ++j) { int idx = base + j; if (idx < N_NODES) s += cnt[idx]; }
    sums[t] = s;
    __syncthreads();
    for (int off = 1; off < 1024; off <<= 1) {
        int v = (t >= off) ? sums[t - off] : 0;
        __syncthreads();
        sums[t] += v;
        __syncthreads();
    }
    int run = (t == 0) ? 0 : sums[t - 1];
    for (int j = 0; j < CH; ++j) {
        int idx = base + j;
        if (idx < N_NODES) { row_start[idx] = run; run += cnt[idx]; }
    }
    if (t == 1023) row_start[N_NODES] = N_EDGES;
}

__global__ __launch_bounds__(256) void k_fill(
    const int* __restrict__ src, const int* __restrict__ dst,
    const int* __restrict__ row_start, int* __restrict__ cursor,
    int* __restrict__ csr_src)
{
    int e = blockIdx.x * 256 + threadIdx.x;
    if (e >= N_EDGES) return;
    int t = dst[e];
    int pos = row_start[t] + atomicAdd(&cursor[t], 1);
    csr_src[pos] = src[e];
}

// W [K][N=128] fp32 -> WT_hi/lo [128][Kpad] bf16 (zero-padded K)
__global__ __launch_bounds__(256) void k_wsplit(
    const float* __restrict__ W, int K, int Kpad,
    u16* __restrict__ Thi, u16* __restrict__ Tlo)
{
    int id = blockIdx.x * 256 + threadIdx.x;
    if (id >= 128 * Kpad) return;
    int n = id / Kpad, k = id - n * Kpad;
    float v = (k < K) ? W[(long)k * HID_C + n] : 0.f;
    float hf; u16 h = f2bf(v, hf);
    float d;  u16 l = f2bf(v - hf, d);
    Thi[id] = h; Tlo[id] = l;
}

// ---------------- split-bf16 MFMA GEMM, N fixed = 128 ----------------
// C[M,128] = f(A)[M,K] @ B[K,128] via 3-term bf16 split (error ~2^-17)
template<bool RELU_A>
__global__ __launch_bounds__(256) void k_gemm_mfma(
    const float* __restrict__ A, const u16* __restrict__ BThi,
    const u16* __restrict__ BTlo, float* __restrict__ C,
    int M, int K, int Kpad, int lda)
{
    using bf16x8 = __attribute__((ext_vector_type(8))) short;
    using f32x4  = __attribute__((ext_vector_type(4))) float;

    __shared__ u16 Ah[128][36];   // +4 pad: frag reads <=2-way bank alias (free)
    __shared__ u16 Al[128][36];

    const int tid  = threadIdx.x;
    const int wave = tid >> 6, lane = tid & 63;
    const int lr   = lane & 15, quad = lane >> 4;
    const int wm   = (wave >> 1) * 64, wn = (wave & 1) * 64;
    const int m0   = blockIdx.x * 128;

    const int srow = tid >> 1;            // staging row 0..127
    const int skh  = (tid & 1) * 16;      // staging k-half
    const bool mok = (m0 + srow) < M;
    const float* arow = A + (long)(m0 + srow) * lda + skh;

    f32x4 acc[4][4];
#pragma unroll
    for (int i = 0; i < 4; ++i)
#pragma unroll
        for (int j = 0; j < 4; ++j)
#pragma unroll
            for (int r = 0; r < 4; ++r) acc[i][j][r] = 0.f;

    const int nk = (K + 31) >> 5;
    for (int t = 0; t < nk; ++t) {
        const int k0 = t * 32;
        // ---- stage A tile: fp32 -> hi/lo bf16 into LDS ----
        float v[16];
        if (k0 + 32 <= K) {
#pragma unroll
            for (int i = 0; i < 16; ++i) v[i] = mok ? arow[k0 + i] : 0.f;
        } else {
#pragma unroll
            for (int i = 0; i < 16; ++i) {
                int gk = k0 + skh + i;
                v[i] = (mok && gk < K) ? arow[k0 + i] : 0.f;
            }
        }
#pragma unroll
        for (int g = 0; g < 4; ++g) {
            u16 h[4], l[4];
#pragma unroll
            for (int c = 0; c < 4; ++c) {
                float x = RELU_A ? fmaxf(v[g * 4 + c], 0.f) : v[g * 4 + c];
                float hf; h[c] = f2bf(x, hf);
                float d;  l[c] = f2bf(x - hf, d);
            }
            *(ushort4*)&Ah[srow][skh + g * 4] = make_ushort4(h[0], h[1], h[2], h[3]);
            *(ushort4*)&Al[srow][skh + g * 4] = make_ushort4(l[0], l[1], l[2], l[3]);
        }
        __syncthreads();

        // ---- B fragments straight from global (L2-resident, pre-transposed) ----
        bf16x8 bh[4], bl[4];
#pragma unroll
        for (int j = 0; j < 4; ++j) {
            long off = (long)(wn + j * 16 + lr) * Kpad + k0 + quad * 8;
            bh[j] = *(const bf16x8*)(BThi + off);
            bl[j] = *(const bf16x8*)(BTlo + off);
        }
        // ---- A fragments from LDS ----
        bf16x8 ah[4], al[4];
#pragma unroll
        for (int i = 0; i < 4; ++i) {
            ah[i] = *(const bf16x8*)&Ah[wm + i * 16 + lr][quad * 8];
            al[i] = *(const bf16x8*)&Al[wm + i * 16 + lr][quad * 8];
        }
#pragma unroll
        for (int i = 0; i < 4; ++i)
#pragma unroll
            for (int j = 0; j < 4; ++j) {
                acc[i][j] = __builtin_amdgcn_mfma_f32_16x16x32_bf16(ah[i], bh[j], acc[i][j], 0, 0, 0);
                acc[i][j] = __builtin_amdgcn_mfma_f32_16x16x32_bf16(ah[i], bl[j], acc[i][j], 0, 0, 0);
                acc[i][j] = __builtin_amdgcn_mfma_f32_16x16x32_bf16(al[i], bh[j], acc[i][j], 0, 0, 0);
            }
        __syncthreads();
    }

    // ---- store: C/D layout col=lane&15, row=quad*4+reg ----
#pragma unroll
    for (int i = 0; i < 4; ++i)
#pragma unroll
        for (int r = 0; r < 4; ++r) {
            int row = m0 + wm + i * 16 + quad * 4 + r;
            if (row < M) {
#pragma unroll
                for (int j = 0; j < 4; ++j)
                    C[(long)row * HID_C + wn + j * 16 + lr] = acc[i][j][r];
            }
        }
}

// ---------------- fp32 tiled GEMM (kept for the small 128x47 layer) ----------------
template<int BN, bool RELU_A, bool BIAS>
__global__ __launch_bounds__(256) void k_gemm(
    const float* __restrict__ A, const float* __restrict__ B,
    const float* __restrict__ bias, float* __restrict__ C,
    int M, int N, int K, int lda, int ldb, int ldc)
{
    constexpr int BM = 64, BK = 16;
    constexpr int TNV = BN / 64;
    __shared__ float As[BK][BM + 4];
    __shared__ float Bs[BK][BN];

    const int tid = threadIdx.x;
    const int tm = tid >> 4;
    const int tn = tid & 15;
    const int m0 = blockIdx.x * BM;
    const int n0 = blockIdx.y * BN;

    float acc[4][TNV * 4];
#pragma unroll
    for (int r = 0; r < 4; ++r)
#pragma unroll
        for (int c = 0; c < TNV * 4; ++c) acc[r][c] = 0.f;

    for (int k0 = 0; k0 < K; k0 += BK) {
        {
            int kk = tid & 15;
            int r0 = tid >> 4;
#pragma unroll
            for (int it = 0; it < 4; ++it) {
                int r = r0 + 16 * it;
                int gm = m0 + r, gk = k0 + kk;
                float v = 0.f;
                if (gm < M && gk < K) v = A[(long)gm * lda + gk];
                if (RELU_A) v = fmaxf(v, 0.f);
                As[kk][r] = v;
            }
        }
        {
            constexpr int KPP = 256 / BN;
            int n  = tid % BN;
            int kb = tid / BN;
#pragma unroll
            for (int it = 0; it < BK / KPP; ++it) {
                int kk = kb + KPP * it;
                int gk = k0 + kk, gn = n0 + n;
                float v = 0.f;
                if (gk < K && gn < N) v = B[(long)gk * ldb + gn];
                Bs[kk][n] = v;
            }
        }
        __syncthreads();
#pragma unroll
        for (int kk = 0; kk < BK; ++kk) {
            float4 a = *(const float4*)&As[kk][tm * 4];
            float av[4] = {a.x, a.y, a.z, a.w};
#pragma unroll
            for (int j = 0; j < TNV; ++j) {
                float4 b = *(const float4*)&Bs[kk][tn * 4 + 64 * j];
                float bv[4] = {b.x, b.y, b.z, b.w};
#pragma unroll
                for (int r = 0; r < 4; ++r)
#pragma unroll
                    for (int c = 0; c < 4; ++c)
                        acc[r][c + j * 4] += av[r] * bv[c];
            }
        }
        __syncthreads();
    }
#pragma unroll
    for (int r = 0; r < 4; ++r) {
        int gm = m0 + tm * 4 + r;
        if (gm >= M) continue;
#pragma unroll
        for (int j = 0; j < TNV; ++j)
#pragma unroll
            for (int c = 0; c < 4; ++c) {
                int gn = n0 + tn * 4 + 64 * j + c;
                if (gn < N) {
                    float v = acc[r][c + j * 4];
                    if (BIAS) v += bias[gn];
                    C[(long)gm * ldc + gn] = v;
                }
            }
    }
}

// ---------------- CSR gather-aggregate ----------------
template<bool RELU_IN, bool BIAS>
__global__ __launch_bounds__(256) void k_aggregate(
    const float2* __restrict__ hw, const int* __restrict__ row_start,
    const int* __restrict__ csr_src, const float* __restrict__ dinv,
    const float* __restrict__ bias, float2* __restrict__ out)
{
    const int tid = threadIdx.x;
    const int node = blockIdx.x * 4 + (tid >> 6);
    if (node >= N_NODES) return;
    const int lane = tid & 63;

    float dt = dinv[node];
    float2 v = hw[(long)node * 64 + lane];
    if (RELU_IN) { v.x = fmaxf(v.x, 0.f); v.y = fmaxf(v.y, 0.f); }
    float2 acc = {0.f, 0.f};

    const int e1 = row_start[node + 1];
    int e = row_start[node];
    for (; e + 2 <= e1; e += 2) {
        int s0 = csr_src[e], s1 = csr_src[e + 1];
        float w0 = dinv[s0], w1 = dinv[s1];
        float2 u0 = hw[(long)s0 * 64 + lane];
        float2 u1 = hw[(long)s1 * 64 + lane];
        if (RELU_IN) {
            u0.x = fmaxf(u0.x, 0.f); u0.y = fmaxf(u0.y, 0.f);
            u1.x = fmaxf(u1.x, 0.f); u1.y = fmaxf(u1.y, 0.f);
        }
        acc.x += w0 * u0.x + w1 * u1.x;
        acc.y += w0 * u0.y + w1 * u1.y;
    }
    if (e < e1) {
        int s0 = csr_src[e];
        float w0 = dinv[s0];
        float2 u0 = hw[(long)s0 * 64 + lane];
        if (RELU_IN) { u0.x = fmaxf(u0.x, 0.f); u0.y = fmaxf(u0.y, 0.f); }
        acc.x += w0 * u0.x;
        acc.y += w0 * u0.y;
    }

    float2 r;
    r.x = dt * (acc.x + dt * v.x);
    r.y = dt * (acc.y + dt * v.y);
    if (BIAS) {
        float2 b = ((const float2*)bias)[lane];
        r.x += b.x; r.y += b.y;
    }
    out[(long)node * 64 + lane] = r;
}

extern "C" void kernel_launch(void* const* d_in, const int* in_sizes, int n_in,
                              void* d_out, int out_size, void* d_ws, size_t ws_size,
                              hipStream_t stream) {
    const float* x  = (const float*)d_in[0];
    const int*   ei = (const int*)  d_in[1];
    const float* W1 = (const float*)d_in[2];
    const float* b1 = (const float*)d_in[3];
    const float* W2 = (const float*)d_in[4];
    const float* b2 = (const float*)d_in[5];
    const float* W3 = (const float*)d_in[6];
    const float* b3 = (const float*)d_in[7];
    float* out = (float*)d_out;
    const int* src = ei;
    const int* dst = ei + N_EDGES;

    char* ws = (char*)d_ws;
    float* dinv      = (float*)(ws + 0);
    int*   cnt       = (int*)  (ws + 200192);
    int*   cursor    = (int*)  (ws + 400384);
    int*   row_start = (int*)  (ws + 600576);
    int*   csr_src   = (int*)  (ws + 801280);
    float* bufA      = (float*)(ws + 7201280);
    float* bufB      = (float*)(ws + 32801280);
    u16*   W1Thi     = (u16*)  (ws + 58401280);   // 128*1440*2 = 368640
    u16*   W1Tlo     = (u16*)  (ws + 58769920);
    u16*   W2Thi     = (u16*)  (ws + 59138560);   // 128*128*2 = 32768
    u16*   W2Tlo     = (u16*)  (ws + 59171328);   // ends 59204096 (~59.2 MB)

    dim3 blk(256);
    const int gN  = (N_NODES + 255) / 256;
    const int gE  = (N_EDGES + 255) / 256;
    const int gAg = (N_NODES + 3) / 4;
    const int gMf = (N_NODES + 127) / 128;        // 391
    dim3 gGemm((N_NODES + 63) / 64, 1);

    // ---- CSR build + norm ----
    k_zero_i<<<gN, blk, 0, stream>>>(cnt, N_NODES);
    k_zero_i<<<gN, blk, 0, stream>>>(cursor, N_NODES);
    k_count<<<gE, blk, 0, stream>>>(dst, cnt);
    k_dinv<<<gN, blk, 0, stream>>>(cnt, dinv);
    k_scan<<<1, 1024, 0, stream>>>(cnt, row_start);
    k_fill<<<gE, blk, 0, stream>>>(src, dst, row_start, cursor, csr_src);

    // ---- weight split/transpose ----
    k_wsplit<<<(128 * KPAD1 + 255) / 256, blk, 0, stream>>>(W1, IN_C, KPAD1, W1Thi, W1Tlo);
    k_wsplit<<<(128 * HID_C + 255) / 256, blk, 0, stream>>>(W2, HID_C, HID_C, W2Thi, W2Tlo);

    // ---- layer 1 ----
    k_gemm_mfma<false><<<gMf, blk, 0, stream>>>(x, W1Thi, W1Tlo, bufA, N_NODES, IN_C, KPAD1, IN_C);
    k_aggregate<false, true><<<gAg, blk, 0, stream>>>(
        (const float2*)bufA, row_start, csr_src, dinv, b1, (float2*)bufB);

    // ---- layer 2 ----
    k_gemm_mfma<true><<<gMf, blk, 0, stream>>>(bufB, W2Thi, W2Tlo, bufA, N_NODES, HID_C, HID_C, HID_C);
    k_aggregate<false, true><<<gAg, blk, 0, stream>>>(
        (const float2*)bufA, row_start, csr_src, dinv, b2, (float2*)bufB);

    // ---- layer 3: out = (A·relu(h2)) @ W3 + b3 ----
    k_aggregate<true, false><<<gAg, blk, 0, stream>>>(
        (const float2*)bufB, row_start, csr_src, dinv, nullptr, (float2*)bufA);
    k_gemm<64, false, true><<<gGemm, blk, 0, stream>>>(
        bufA, W3, b3, out, N_NODES, OUT_C, HID_C, HID_C, OUT_C, OUT_C);
}